// Round 5
// baseline (193.368 us; speedup 1.0000x reference)
//
#include <hip/hip_runtime.h>
#include <hip/hip_bf16.h>

// KAN linear == GEMM M=8192, N=512, K=4096 (8 Chebyshev/silu feats per input,
// basis_0 folded into bias). Round 5: ZERO-LDS, ZERO-BARRIER dataflow GEMM.
//  - A-frags generated per-lane in registers (one GEN chunk == one 16x16x32 A-frag)
//  - B-frags loaded directly from L2-resident W (16 contiguous B/lane, 16 dense lines/wave)
//  - block 128x128, 4 waves of 64x64, grid 256 = 1 block/CU, prefetch depth 1 iter
#define IN_FEAT 512
#define OUT_FEAT 512
#define NTOK 8192
#define KDIM 4096

typedef short bf16x8 __attribute__((ext_vector_type(8)));
typedef float f32x4 __attribute__((ext_vector_type(4)));

static __device__ inline short f2bf(float f) {
    union { float f; unsigned u; } v; v.f = f;
    unsigned u = v.u;
    u += 0x7fffu + ((u >> 16) & 1u);   // RNE
    return (short)(u >> 16);
}

// pack two fp32 -> bf16 pair (round-half-up): 2 adds + v_perm
static __device__ inline unsigned pack2bf(float f0, float f1) {
    union { float f; unsigned u; } a, b; a.f = f0; b.f = f1;
    return __builtin_amdgcn_perm(b.u + 0x8000u, a.u + 0x8000u, 0x07060302u);
}

// 8 basis features of one (token,input): [silu(xc), xc, T2..T7] as bf16x8 (one A-frag)
static __device__ inline bf16x8 gen_chunk(float xv) {
    float xc = fminf(fmaxf(xv, -1.f), 1.f);
    float e  = __expf(-xc);
    float bse = xc * __builtin_amdgcn_rcpf(1.f + e);
    float b2 = 2.f * xc * xc - 1.f;
    float b3 = 2.f * xc * b2 - 1.f;
    float b4 = 2.f * xc * b3 - 1.f;
    float b5 = 2.f * xc * b4 - 1.f;
    float b6 = 2.f * xc * b5 - 1.f;
    float b7 = 2.f * xc * b6 - 1.f;
    union { uint4 u; bf16x8 v; } r;
    r.u.x = pack2bf(bse, xc);
    r.u.y = pack2bf(b2, b3);
    r.u.z = pack2bf(b4, b5);
    r.u.w = pack2bf(b6, b7);
    return r.v;
}

// ---------------- prep: W bf16 [512 x 4096] + folded bias ----------------
__global__ __launch_bounds__(256) void kan_prep(
    const float* __restrict__ coeff, const float* __restrict__ scale_base,
    const float* __restrict__ scale_spline, const float* __restrict__ base_bias,
    short* __restrict__ Wb, float* __restrict__ bias)
{
    int o = blockIdx.x;
    int tid = threadIdx.x;
    float local = 0.f;
#pragma unroll
    for (int rep = 0; rep < 2; ++rep) {
        int i = tid + rep * 256;
        size_t oi = (size_t)o * IN_FEAT + i;
        const float4* c4 = (const float4*)(coeff + oi * 8);
        float4 ca = c4[0], cb = c4[1];
        float ss = scale_spline[oi];
        float sb = scale_base[oi];
        local += base_bias[oi] + ss * ca.x;
        bf16x8 w;
        w[0] = f2bf(sb);
        w[1] = f2bf(ss * ca.y); w[2] = f2bf(ss * ca.z); w[3] = f2bf(ss * ca.w);
        w[4] = f2bf(ss * cb.x); w[5] = f2bf(ss * cb.y); w[6] = f2bf(ss * cb.z);
        w[7] = f2bf(ss * cb.w);
        *(bf16x8*)(Wb + (size_t)o * KDIM + (size_t)i * 8) = w;
    }
    __shared__ float red[4];
    for (int off = 32; off > 0; off >>= 1) local += __shfl_down(local, off, 64);
    int lane = tid & 63, wv = tid >> 6;
    if (lane == 0) red[wv] = local;
    __syncthreads();
    if (tid == 0) bias[o] = red[0] + red[1] + red[2] + red[3];
}

// ---------------- zero-LDS barrier-free GEMM ----------------
__global__ __launch_bounds__(256, 1) void kan_gemm5(
    const float* __restrict__ x, const short* __restrict__ Wb,
    const float* __restrict__ bias, float* __restrict__ out)
{
    int tid = threadIdx.x;
    int nb = blockIdx.x & 3;         // 4 n-blocks
    int mb = blockIdx.x >> 2;        // 64 m-blocks
    int m0 = mb * 128, o0 = nb * 128;

    int lane = tid & 63, wv = tid >> 6;
    int wm = wv & 1, wn = wv >> 1;   // 2x2 waves, each 64x64
    int qd = lane >> 4, ln15 = lane & 15;

    f32x4 acc[4][4];
#pragma unroll
    for (int a = 0; a < 4; ++a)
#pragma unroll
        for (int b = 0; b < 4; ++b) acc[a][b] = (f32x4)0.f;

    // per-lane source pointers
    const float* xb[4];
#pragma unroll
    for (int fm = 0; fm < 4; ++fm)
        xb[fm] = x + (size_t)(m0 + wm * 64 + fm * 16 + ln15) * IN_FEAT + qd;
    const short* wr[4];
#pragma unroll
    for (int fn = 0; fn < 4; ++fn)
        wr[fn] = Wb + (size_t)(o0 + wn * 64 + fn * 16 + ln15) * KDIM + qd * 8;

    // double-buffered register operand sets: index [f*2 + kq]
    float  xc_[8];
    bf16x8 bc_[8];
#pragma unroll
    for (int fm = 0; fm < 4; ++fm)
#pragma unroll
        for (int kq = 0; kq < 2; ++kq)
            xc_[fm * 2 + kq] = xb[fm][kq * 4];
#pragma unroll
    for (int fn = 0; fn < 4; ++fn)
#pragma unroll
        for (int kq = 0; kq < 2; ++kq)
            bc_[fn * 2 + kq] = *(const bf16x8*)(wr[fn] + kq * 32);

#pragma unroll 2
    for (int it = 0; it < IN_FEAT / 8; ++it) {
        int itn = (it + 1) & 63;     // wrap: last prefetch re-reads iter 0 (cached, unused)
        // ---- prefetch next iteration's x and B into the alternate set ----
        float  xn_[8];
        bf16x8 bn_[8];
#pragma unroll
        for (int fm = 0; fm < 4; ++fm)
#pragma unroll
            for (int kq = 0; kq < 2; ++kq)
                xn_[fm * 2 + kq] = xb[fm][itn * 8 + kq * 4];
#pragma unroll
        for (int fn = 0; fn < 4; ++fn)
#pragma unroll
            for (int kq = 0; kq < 2; ++kq)
                bn_[fn * 2 + kq] = *(const bf16x8*)(wr[fn] + itn * 64 + kq * 32);

        // ---- compute: gen A-frags in regs, MFMA against current B ----
#pragma unroll
        for (int kq = 0; kq < 2; ++kq) {
            bf16x8 af[4];
#pragma unroll
            for (int fm = 0; fm < 4; ++fm)
                af[fm] = gen_chunk(xc_[fm * 2 + kq]);
#pragma unroll
            for (int fm = 0; fm < 4; ++fm)
#pragma unroll
                for (int fn = 0; fn < 4; ++fn)
                    acc[fm][fn] = __builtin_amdgcn_mfma_f32_16x16x32_bf16(
                        af[fm], bc_[fn * 2 + kq], acc[fm][fn], 0, 0, 0);
        }
        // rotate buffers (register renaming after unroll-by-2)
#pragma unroll
        for (int i = 0; i < 8; ++i) { xc_[i] = xn_[i]; bc_[i] = bn_[i]; }
    }

    // ---- epilogue: C/D row = qd*4+reg, col = ln15 ----
#pragma unroll
    for (int fn = 0; fn < 4; ++fn) {
        int o = o0 + wn * 64 + fn * 16 + ln15;
        float bv = bias[o];
#pragma unroll
        for (int fm = 0; fm < 4; ++fm) {
            int r0 = m0 + wm * 64 + fm * 16 + qd * 4;
#pragma unroll
            for (int r = 0; r < 4; ++r)
                out[(size_t)(r0 + r) * OUT_FEAT + o] = acc[fm][fn][r] + bv;
        }
    }
}

extern "C" void kernel_launch(void* const* d_in, const int* in_sizes, int n_in,
                              void* d_out, int out_size, void* d_ws, size_t ws_size,
                              hipStream_t stream) {
    const float* x            = (const float*)d_in[0];
    const float* coeff        = (const float*)d_in[1];
    const float* scale_base   = (const float*)d_in[2];
    const float* scale_spline = (const float*)d_in[3];
    const float* base_bias    = (const float*)d_in[4];
    float* out = (float*)d_out;

    short* Wb   = (short*)d_ws;                                  // 4 MB
    float* bias = (float*)((char*)d_ws + (size_t)OUT_FEAT * KDIM * 2);

    kan_prep<<<OUT_FEAT, 256, 0, stream>>>(coeff, scale_base, scale_spline, base_bias, Wb, bias);
    kan_gemm5<<<(NTOK / 128) * (OUT_FEAT / 128), 256, 0, stream>>>(x, Wb, bias, out);
}